// Round 4
// baseline (27.961 us; speedup 1.0000x reference)
//
#include <hip/hip_runtime.h>

#define IN_SIZE 11
#define HID 16
#define FEAT 18
#define TSTEPS 18

__device__ __forceinline__ float fast_rcp(float v) { return __builtin_amdgcn_rcpf(v); }

// broadcast a float from a fixed lane via v_readlane (VALU/SALU path, no DS)
__device__ __forceinline__ float rl(float v, int lane) {
    return __int_as_float(__builtin_amdgcn_readlane(__float_as_int(v), lane));
}

// One WAVE per graph. Lane wl owns gate row wl (r=wl>>4 in torch order i,f,g,o;
// u=wl&15 hidden unit). Inner loop uses only 3 ds-swizzles per step; h is
// broadcast through SGPRs via v_readlane; x-contribution precomputed per lane.
extern "C" __global__ __launch_bounds__(256, 4)
void tgnn_lstm_fused(const float* __restrict__ x,
                     const float* __restrict__ W_ih,
                     const float* __restrict__ W_hh,
                     const float* __restrict__ b_ih,
                     const float* __restrict__ b_hh,
                     const float* __restrict__ W_fc,
                     const float* __restrict__ b_fc,
                     const int* __restrict__ edge_index,
                     const int* __restrict__ edge_attr,
                     const int* __restrict__ batch,
                     float* __restrict__ out,
                     int E, int B)
{
    const int wl  = threadIdx.x & 63;
    const int g   = (blockIdx.x * blockDim.x + threadIdx.x) >> 6;  // global wave id
    const int u   = wl & 15;
    const int r   = wl >> 4;
    const int row = wl;                 // row = r*16+u == wl

    // ---- per-lane weights (issued early; latency overlaps the search) ----
    float wih[IN_SIZE], whh[HID];
#pragma unroll
    for (int k = 0; k < IN_SIZE; ++k) wih[k] = W_ih[row * FEAT + k];
#pragma unroll
    for (int v = 0; v < HID; ++v) whh[v] = W_hh[row * HID + v];
    const float bias = b_ih[row] + b_hh[row];
    const float wfc  = W_fc[row];
    const float bfc  = b_fc[r];

    // ---- dual interleaved 64-ary lower_bound: first=lb(g), end=lb(g+1) ----
    const int tgt1 = g, tgt2 = g + 1;
    int lo1 = 0, hi1 = E, lo2 = 0, hi2 = E;
    while ((hi1 - lo1) > 64 || (hi2 - lo2) > 64) {
        const unsigned n1r = (unsigned)(hi1 - lo1);
        const unsigned n2r = (unsigned)(hi2 - lo2);
        const int p1 = lo1 + (int)((n1r * (unsigned)wl) >> 6);
        const int p2 = lo2 + (int)((n2r * (unsigned)wl) >> 6);
        const int b1 = batch[p1];
        const int b2 = batch[p2];
        const int c1 = __popcll(__ballot(b1 < tgt1));
        const int c2 = __popcll(__ballot(b2 < tgt2));
        const int nlo1 = c1 ? (lo1 + (int)((n1r * (unsigned)(c1 - 1)) >> 6) + 1) : lo1;
        const int nhi1 = (c1 < 64) ? (lo1 + (int)((n1r * (unsigned)c1) >> 6)) : hi1;
        const int nlo2 = c2 ? (lo2 + (int)((n2r * (unsigned)(c2 - 1)) >> 6) + 1) : lo2;
        const int nhi2 = (c2 < 64) ? (lo2 + (int)((n2r * (unsigned)c2) >> 6)) : hi2;
        lo1 = nlo1; hi1 = nhi1; lo2 = nlo2; hi2 = nhi2;
    }
    {
        const int n1r = hi1 - lo1, n2r = hi2 - lo2;   // <= 64
        int p1 = lo1 + ((wl < n1r) ? wl : 0);
        int p2 = lo2 + ((wl < n2r) ? wl : 0);
        if (p1 > E - 1) p1 = E - 1;
        if (p2 > E - 1) p2 = E - 1;
        const int b1 = batch[p1];
        const int b2 = batch[p2];
        lo1 += __popcll(__ballot((wl < n1r) && (b1 < tgt1)));
        lo2 += __popcll(__ballot((wl < n2r) && (b2 < tgt2)));
    }
    const int first = lo1;
    int cnt = lo2 - first;
    cnt = (cnt < 0) ? 0 : ((cnt > TSTEPS) ? TSTEPS : cnt);

    // ---- gather: lane t (t<18) holds step t's 11 summed x-features + attr ----
    int n1 = 0, n2 = 0, ea = 0;
    if (wl < TSTEPS) {
        int j = first + wl;
        if (j > E - 1) j = E - 1;
        n1 = edge_index[j];
        n2 = edge_index[E + j];
        ea = edge_attr[j];            // in [0,7) even when clamped
    }
    float f[IN_SIZE];
    {
        const float* xa = x + (long)n1 * IN_SIZE;
        const float* xb = x + (long)n2 * IN_SIZE;
#pragma unroll
        for (int k = 0; k < IN_SIZE; ++k) f[k] = xa[k] + xb[k];
    }
    if (wl >= cnt) {                  // covers invalid steps AND lanes >= 18
#pragma unroll
        for (int k = 0; k < IN_SIZE; ++k) f[k] = 0.0f;
    }

    // ---- prologue: a_in[t] = bias + x_t . wih_row + onehot-weight, per lane ----
    float ain[TSTEPS];
#pragma unroll
    for (int t = 0; t < TSTEPS; ++t) {
        const int eat = __builtin_amdgcn_readlane(ea, t);       // uniform
        const float w1 = W_ih[row * FEAT + IN_SIZE + eat];      // L1-hot (4.6 KB)
        float a = bias + ((t < cnt) ? w1 : 0.0f);
#pragma unroll
        for (int k = 0; k < IN_SIZE; ++k)
            a = fmaf(rl(f[k], t), wih[k], a);
        ain[t] = a;
    }

    // ---- LSTM: per step 16 readlane + 16 FMA + 1 act + 3 swizzles ----
    // own-gate activation, branchless: r!=2 -> sigmoid(a); r==2 -> tanh(a)=2*sig(2a)-1
    const float sa = (r == 2) ? -2.0f : -1.0f;
    const float ma = (r == 2) ?  2.0f :  1.0f;
    const float oa = (r == 2) ? -1.0f :  0.0f;

    float h = 0.0f, c = 0.0f;
#pragma unroll
    for (int t = 0; t < TSTEPS; ++t) {
        float a;
        if (t == 0) {
            a = ain[0];               // h == 0
        } else {
            float A0 = ain[t], A1 = 0.0f, A2 = 0.0f, A3 = 0.0f;
#pragma unroll
            for (int v = 0; v < HID; v += 4) {
                A0 = fmaf(rl(h, v + 0), whh[v + 0], A0);
                A1 = fmaf(rl(h, v + 1), whh[v + 1], A1);
                A2 = fmaf(rl(h, v + 2), whh[v + 2], A2);
                A3 = fmaf(rl(h, v + 3), whh[v + 3], A3);
            }
            a = (A0 + A1) + (A2 + A3);
        }
        const float act = fmaf(ma, fast_rcp(1.0f + __expf(sa * a)), oa);
        // allgather gates within {u, u+16, u+32, u+48}; valid in lanes 0..15:
        const float s1 = __shfl_xor(act, 16, 64);   // sigma(f)
        const float s2 = __shfl_xor(act, 32, 64);   // tanh(g)
        const float s3 = __shfl_xor(s1, 32, 64);    // sigma(o)
        c = fmaf(s1, c, act * s2);                  // (lanes 0..15 valid)
        const float th = fmaf(2.0f, fast_rcp(1.0f + __expf(-2.0f * c)), -1.0f);
        h = s3 * th;                                // h[u] valid in lanes 0..15
    }

    // ---- fc epilogue ----
    const float hb = __shfl(h, u, 64);              // lane wl <- h[u] from lane u
    float p = hb * wfc;                             // W_fc[r][u] == W_fc[row]
#pragma unroll
    for (int m = 8; m >= 1; m >>= 1) p += __shfl_xor(p, m, 16);
    if (u == 0 && g < B) out[g * 4 + r] = p + bfc;
}

extern "C" void kernel_launch(void* const* d_in, const int* in_sizes, int n_in,
                              void* d_out, int out_size, void* d_ws, size_t ws_size,
                              hipStream_t stream) {
    const float* x     = (const float*)d_in[0];
    const float* W_ih  = (const float*)d_in[1];
    const float* W_hh  = (const float*)d_in[2];
    const float* b_ih  = (const float*)d_in[3];
    const float* b_hh  = (const float*)d_in[4];
    const float* W_fc  = (const float*)d_in[5];
    const float* b_fc  = (const float*)d_in[6];
    const int* edge_index = (const int*)d_in[7];
    const int* edge_attr  = (const int*)d_in[8];
    const int* batch      = (const int*)d_in[9];

    const int E = in_sizes[8];       // N_EDGES
    const int B = out_size / 4;      // N_GRAPHS

    const int grid = (B + 3) / 4;    // 4 graphs (waves) per 256-thread block
    tgnn_lstm_fused<<<grid, 256, 0, stream>>>(x, W_ih, W_hh, b_ih, b_hh,
                                              W_fc, b_fc,
                                              edge_index, edge_attr, batch,
                                              (float*)d_out, E, B);
}